// Round 7
// baseline (53.699 us; speedup 1.0000x reference)
//
#include <hip/hip_runtime.h>
#include <hip/hip_bf16.h>

typedef float  f32x4 __attribute__((ext_vector_type(4)));
typedef short  s16x8 __attribute__((ext_vector_type(8)));
typedef __bf16 b16x8 __attribute__((ext_vector_type(8)));
typedef __bf16 b16x2 __attribute__((ext_vector_type(2)));

#define NROWS  8192
#define ROWSPW 4     // rows per wave
#define NWAVES (NROWS / ROWSPW)   // 2048 waves = 512 blocks x 4
#define ROWP   72    // XT pitch (shorts)

__device__ __forceinline__ f32x4 mfma_bf16(s16x8 a, s16x8 b, f32x4 c) {
    return __builtin_amdgcn_mfma_f32_16x16x32_bf16(
        __builtin_bit_cast(b16x8, a), __builtin_bit_cast(b16x8, b), c, 0, 0, 0);
}

__device__ __forceinline__ short f2b(float f) {
    return __builtin_bit_cast(short, (__bf16)f);
}

__device__ __forceinline__ s16x8 pack8(f32x4 a, f32x4 b) {
    s16x8 r;
    r[0] = f2b(a[0]); r[1] = f2b(a[1]); r[2] = f2b(a[2]); r[3] = f2b(a[3]);
    r[4] = f2b(b[0]); r[5] = f2b(b[1]); r[6] = f2b(b[2]); r[7] = f2b(b[3]);
    return r;
}

__device__ __forceinline__ int2 pack4(f32x4 v) {
    b16x2 p0; p0[0] = (__bf16)v[0]; p0[1] = (__bf16)v[1];
    b16x2 p1; p1[0] = (__bf16)v[2]; p1[1] = (__bf16)v[3];
    int2 r;
    r.x = __builtin_bit_cast(int, p0);
    r.y = __builtin_bit_cast(int, p1);
    return r;
}

// id8 k-map: slot s <- col colbase + s
__device__ __forceinline__ s16x8 load_frag_id(const float* __restrict__ mat, int row, int colbase) {
    const float* p = mat + row * 64 + colbase;
    return pack8(*reinterpret_cast<const f32x4*>(p), *reinterpret_cast<const f32x4*>(p + 4));
}

// kappa k-map: slot s<4 <- col cb + g*4 + s ; slot s>=4 <- col cb + 16 + g*4 + (s-4)
__device__ __forceinline__ s16x8 load_frag_k(const float* __restrict__ mat, int row, int cb, int g) {
    const float* p = mat + row * 64 + cb + g * 4;
    return pack8(*reinterpret_cast<const f32x4*>(p), *reinterpret_cast<const f32x4*>(p + 16));
}

// Per row n: Out = W1 * X * W2^T (all 64x64).
// Pipelined: 4 rows/wave; next row's 16 coalesced 1KB loads are issued into
// registers right after the current row's fragments are read from LDS, so HBM
// latency hides under stage-1 + stage-2. XT (bf16, pitch 72) and OL (f32,
// 16x64 XOR-quad-swizzled) are SEPARATE buffers -> no reuse fences.
// Stage 1: T = X @ W2^T (id8 both sides), nt-outer 4-acc window.
// Register transpose -> A-frags of T^T (kappa). Stage 2: Out^T = T^T @ W1^T
// (kappa both sides); per it-tile: OL round-trip -> 4 x 1KB contiguous stores.
__global__ __launch_bounds__(256, 2) void kron2_kernel(
    const float* __restrict__ data, const float* __restrict__ W1,
    const float* __restrict__ W2, float* __restrict__ out)
{
    __shared__ short xts[4][64][ROWP];
    __shared__ float ols[4][16][64];
    const int lane = threadIdx.x & 63;
    const int wv   = threadIdx.x >> 6;
    const int c    = lane & 15;
    const int g    = lane >> 4;
    short (*XT)[ROWP] = xts[wv];
    float (*OL)[64]   = ols[wv];

    // Weight fragments, once per wave (amortized over 4 rows).
    s16x8 w2f[4][2], w1f[4][2];
    #pragma unroll
    for (int t = 0; t < 4; ++t)
      #pragma unroll
      for (int kh = 0; kh < 2; ++kh) {
        w2f[t][kh] = load_frag_id(W2, t * 16 + c, kh * 32 + g * 8);  // id8
        w1f[t][kh] = load_frag_k (W1, t * 16 + c, kh * 32, g);       // kappa
      }

    const int w = (int)((blockIdx.x * blockDim.x + threadIdx.x) >> 6);

    // ---- prologue: coalesced load of row 0 (16 x 1KB lane-contiguous) ----
    f32x4 v[16];
    {
        const float* X = data + (size_t)(w * ROWSPW) * 4096;
        #pragma unroll
        for (int j = 0; j < 16; ++j)
            v[j] = *reinterpret_cast<const f32x4*>(X + j * 256 + lane * 4);
    }

    #pragma unroll
    for (int rr = 0; rr < ROWSPW; ++rr) {
        const int n = w * ROWSPW + rr;

        // ---- stage v -> XT (bf16, pitch ROWP) ----
        #pragma unroll
        for (int j = 0; j < 16; ++j)
            *reinterpret_cast<int2*>(&XT[j * 4 + g][c * 4]) = pack4(v[j]);

        // ---- X fragments from LDS (id8 map) ----
        s16x8 xa[4][2];
        #pragma unroll
        for (int mt = 0; mt < 4; ++mt)
          #pragma unroll
          for (int kh = 0; kh < 2; ++kh)
            xa[mt][kh] = *reinterpret_cast<const s16x8*>(&XT[mt * 16 + c][kh * 32 + g * 8]);

        // ---- prefetch next row into v (in flight during all compute below) ----
        if (rr + 1 < ROWSPW) {
            const float* Xn = data + (size_t)(n + 1) * 4096;
            #pragma unroll
            for (int j = 0; j < 16; ++j)
                v[j] = *reinterpret_cast<const f32x4*>(Xn + j * 256 + lane * 4);
        }

        // ---- stage 1: T = X @ W2^T, nt-outer; build T^T A-frags (kappa) ----
        s16x8 a2[4][2];
        #pragma unroll
        for (int nt = 0; nt < 4; ++nt) {
            f32x4 acc[4];
            #pragma unroll
            for (int mt = 0; mt < 4; ++mt) {
                f32x4 a = {0.f, 0.f, 0.f, 0.f};
                a = mfma_bf16(xa[mt][0], w2f[nt][0], a);
                a = mfma_bf16(xa[mt][1], w2f[nt][1], a);
                acc[mt] = a;
            }
            a2[nt][0] = pack8(acc[0], acc[1]);
            a2[nt][1] = pack8(acc[2], acc[3]);
        }

        // ---- stage 2: Out^T = T^T @ W1^T; per it-tile OL round-trip + stores ----
        #pragma unroll
        for (int it = 0; it < 4; ++it) {
            #pragma unroll
            for (int jt = 0; jt < 4; ++jt) {
                f32x4 a = {0.f, 0.f, 0.f, 0.f};
                a = mfma_bf16(a2[jt][0], w1f[it][0], a);
                a = mfma_bf16(a2[jt][1], w1f[it][1], a);
                // lane holds Out[it*16+c][jt*16+g*4 + 0..3]; swizzled OL write
                *reinterpret_cast<f32x4*>(&OL[c][(jt * 16 + g * 4) ^ (c * 4)]) = a;
            }
            // lane-contiguous read-back + 4 x 1KB global stores
            #pragma unroll
            for (int s = 0; s < 4; ++s) {
                const int R = s * 4 + g;            // logical OL row
                const int C = c * 4;                // logical col (dwords)
                f32x4 o = *reinterpret_cast<const f32x4*>(&OL[R][C ^ (R * 4)]);
                *reinterpret_cast<f32x4*>(
                    out + (size_t)n * 4096 + it * 1024 + s * 256 + lane * 4) = o;
            }
        }
    }
}

extern "C" void kernel_launch(void* const* d_in, const int* in_sizes, int n_in,
                              void* d_out, int out_size, void* d_ws, size_t ws_size,
                              hipStream_t stream) {
    const float* data = (const float*)d_in[0];
    const float* W1   = (const float*)d_in[1];
    const float* W2   = (const float*)d_in[2];
    float* out        = (float*)d_out;
    dim3 grid(NWAVES / 4), block(256);   // 512 blocks x 4 waves x 4 rows
    hipLaunchKernelGGL(kron2_kernel, grid, block, 0, stream, data, W1, W2, out);
}

// Round 8
// 50.557 us; speedup vs baseline: 1.0622x; 1.0622x over previous
//
#include <hip/hip_runtime.h>
#include <hip/hip_bf16.h>

typedef float  f32x4 __attribute__((ext_vector_type(4)));
typedef short  s16x8 __attribute__((ext_vector_type(8)));
typedef __bf16 b16x8 __attribute__((ext_vector_type(8)));
typedef __bf16 b16x2 __attribute__((ext_vector_type(2)));

#define NROWS  8192
#define ROWP   72      // X staging pitch (shorts)
#define WBYTES 9216    // per-wave LDS: union of X-stage (64*72*2) and O-stage (8KB)

__device__ __forceinline__ f32x4 mfma_bf16(s16x8 a, s16x8 b, f32x4 c) {
    return __builtin_amdgcn_mfma_f32_16x16x32_bf16(
        __builtin_bit_cast(b16x8, a), __builtin_bit_cast(b16x8, b), c, 0, 0, 0);
}

__device__ __forceinline__ short f2b(float f) {
    return __builtin_bit_cast(short, (__bf16)f);
}

__device__ __forceinline__ s16x8 pack8(f32x4 a, f32x4 b) {
    s16x8 r;
    r[0] = f2b(a[0]); r[1] = f2b(a[1]); r[2] = f2b(a[2]); r[3] = f2b(a[3]);
    r[4] = f2b(b[0]); r[5] = f2b(b[1]); r[6] = f2b(b[2]); r[7] = f2b(b[3]);
    return r;
}

__device__ __forceinline__ int2 pack4(f32x4 v) {
    b16x2 p0; p0[0] = (__bf16)v[0]; p0[1] = (__bf16)v[1];
    b16x2 p1; p1[0] = (__bf16)v[2]; p1[1] = (__bf16)v[3];
    int2 r;
    r.x = __builtin_bit_cast(int, p0);
    r.y = __builtin_bit_cast(int, p1);
    return r;
}

// id8 k-map: slot s <- col colbase + s
__device__ __forceinline__ s16x8 load_frag_id(const float* __restrict__ mat, int row, int colbase) {
    const float* p = mat + row * 64 + colbase;
    return pack8(*reinterpret_cast<const f32x4*>(p), *reinterpret_cast<const f32x4*>(p + 4));
}

// kappa k-map: slot s<4 <- col cb + g*4 + s ; slot s>=4 <- col cb + 16 + g*4 + (s-4)
__device__ __forceinline__ s16x8 load_frag_k(const float* __restrict__ mat, int row, int cb, int g) {
    const float* p = mat + row * 64 + cb + g * 4;
    return pack8(*reinterpret_cast<const f32x4*>(p), *reinterpret_cast<const f32x4*>(p + 16));
}

// R8 = R6 (proven 50.4us: coalesced loads, LDS frag staging, register-transpose,
// OL store-coalescing, 1024 blocks -> 4 blocks/CU) + register prefetch of the
// wave's second row, issued right after the first row's fragments leave LDS so
// the 16KB load stays in flight across stage-1 + stage-2 + stores.
__global__ __launch_bounds__(256) void kron2_kernel(
    const float* __restrict__ data, const float* __restrict__ W1,
    const float* __restrict__ W2, float* __restrict__ out)
{
    __shared__ __align__(16) char smem[4][WBYTES];
    const int lane = threadIdx.x & 63;
    const int wv   = threadIdx.x >> 6;
    const int c    = lane & 15;
    const int g    = lane >> 4;
    short (*XT)[ROWP] = reinterpret_cast<short(*)[ROWP]>(&smem[wv][0]);
    float* OL         = reinterpret_cast<float*>(&smem[wv][0]);

    const int w = (int)((blockIdx.x * blockDim.x + threadIdx.x) >> 6);

    // ---- prologue: issue row-0 loads FIRST (oldest in flight) ----
    f32x4 v[16];
    {
        const float* X0 = data + (size_t)(w * 2) * 4096;
        #pragma unroll
        for (int j = 0; j < 16; ++j)
            v[j] = *reinterpret_cast<const f32x4*>(X0 + j * 256 + lane * 4);
    }

    // Weight fragments (L2-hot), once per wave.
    s16x8 w2f[4][2], w1f[4][2];
    #pragma unroll
    for (int t = 0; t < 4; ++t)
      #pragma unroll
      for (int kh = 0; kh < 2; ++kh) {
        w2f[t][kh] = load_frag_id(W2, t * 16 + c, kh * 32 + g * 8);  // id8
        w1f[t][kh] = load_frag_k (W1, t * 16 + c, kh * 32, g);       // kappa
      }

    #pragma unroll
    for (int rr = 0; rr < 2; ++rr) {
        const int n = w * 2 + rr;

        // ---- stage v -> XT (bf16, pitch ROWP) ----
        #pragma unroll
        for (int j = 0; j < 16; ++j)
            *reinterpret_cast<int2*>(&XT[j * 4 + g][c * 4]) = pack4(v[j]);

        // ---- X fragments from LDS (id8 map) ----
        s16x8 xa[4][2];
        #pragma unroll
        for (int mt = 0; mt < 4; ++mt)
          #pragma unroll
          for (int kh = 0; kh < 2; ++kh)
            xa[mt][kh] = *reinterpret_cast<const s16x8*>(&XT[mt * 16 + c][kh * 32 + g * 8]);

        // ---- prefetch second row; in flight across all compute below ----
        if (rr == 0) {
            const float* Xn = data + (size_t)(n + 1) * 4096;
            #pragma unroll
            for (int j = 0; j < 16; ++j)
                v[j] = *reinterpret_cast<const f32x4*>(Xn + j * 256 + lane * 4);
        }

        // ---- stage 1: T = X @ W2^T (id8), nt-outer; T^T A-frags via kappa ----
        s16x8 a2[4][2];
        #pragma unroll
        for (int nt = 0; nt < 4; ++nt) {
            f32x4 acc[4];
            #pragma unroll
            for (int mt = 0; mt < 4; ++mt) {
                f32x4 a = {0.f, 0.f, 0.f, 0.f};
                a = mfma_bf16(xa[mt][0], w2f[nt][0], a);
                a = mfma_bf16(xa[mt][1], w2f[nt][1], a);
                acc[mt] = a;
            }
            a2[nt][0] = pack8(acc[0], acc[1]);
            a2[nt][1] = pack8(acc[2], acc[3]);
        }

        // ---- stage 2 + coalesced store, 32-row halves through OL (union) ----
        #pragma unroll
        for (int h2 = 0; h2 < 2; ++h2) {
            #pragma unroll
            for (int q = 0; q < 2; ++q) {
                const int it = h2 * 2 + q;
                #pragma unroll
                for (int jt = 0; jt < 4; ++jt) {
                    f32x4 a = {0.f, 0.f, 0.f, 0.f};
                    a = mfma_bf16(a2[jt][0], w1f[it][0], a);
                    a = mfma_bf16(a2[jt][1], w1f[it][1], a);
                    const int prow = q * 16 + c;
                    const int pcol = (jt * 16 + g * 4) ^ (c * 4);
                    *reinterpret_cast<f32x4*>(&OL[prow * 64 + pcol]) = a;
                }
            }
            #pragma unroll
            for (int s = 0; s < 8; ++s) {
                const int prow = s * 4 + (lane >> 4);
                const int pcol = ((lane & 15) * 4) ^ ((prow & 15) * 4);
                f32x4 o = *reinterpret_cast<const f32x4*>(&OL[prow * 64 + pcol]);
                *reinterpret_cast<f32x4*>(
                    out + (size_t)n * 4096 + h2 * 2048 + s * 256 + lane * 4) = o;
            }
            // compiler-only fence for OL region reuse (HW LDS is in-order per wave)
            asm volatile("" ::: "memory");
            __builtin_amdgcn_sched_barrier(0);
        }
        asm volatile("" ::: "memory");
        __builtin_amdgcn_sched_barrier(0);
    }
}

extern "C" void kernel_launch(void* const* d_in, const int* in_sizes, int n_in,
                              void* d_out, int out_size, void* d_ws, size_t ws_size,
                              hipStream_t stream) {
    const float* data = (const float*)d_in[0];
    const float* W1   = (const float*)d_in[1];
    const float* W2   = (const float*)d_in[2];
    float* out        = (float*)d_out;
    dim3 grid(NROWS / 8), block(256);   // 1024 blocks x 4 waves x 2 rows
    hipLaunchKernelGGL(kron2_kernel, grid, block, 0, stream, data, W1, W2, out);
}

// Round 9
// 46.834 us; speedup vs baseline: 1.1466x; 1.0795x over previous
//
#include <hip/hip_runtime.h>
#include <hip/hip_bf16.h>

typedef float  f32x4 __attribute__((ext_vector_type(4)));
typedef short  s16x4 __attribute__((ext_vector_type(4)));
typedef short  s16x8 __attribute__((ext_vector_type(8)));
typedef __bf16 b16x8 __attribute__((ext_vector_type(8)));
typedef __bf16 b16x2 __attribute__((ext_vector_type(2)));

#define NROWS  8192
#define ROWP   72      // X staging pitch (shorts)
#define WBYTES 9216    // per-wave LDS region: union of X-stage (64*72*2) / O-stage (8KB) / weight-stage

__device__ __forceinline__ f32x4 mfma_bf16(s16x8 a, s16x8 b, f32x4 c) {
    return __builtin_amdgcn_mfma_f32_16x16x32_bf16(
        __builtin_bit_cast(b16x8, a), __builtin_bit_cast(b16x8, b), c, 0, 0, 0);
}

__device__ __forceinline__ short f2b(float f) {
    return __builtin_bit_cast(short, (__bf16)f);
}

__device__ __forceinline__ s16x8 pack8(f32x4 a, f32x4 b) {
    s16x8 r;
    r[0] = f2b(a[0]); r[1] = f2b(a[1]); r[2] = f2b(a[2]); r[3] = f2b(a[3]);
    r[4] = f2b(b[0]); r[5] = f2b(b[1]); r[6] = f2b(b[2]); r[7] = f2b(b[3]);
    return r;
}

__device__ __forceinline__ int2 pack4(f32x4 v) {
    b16x2 p0; p0[0] = (__bf16)v[0]; p0[1] = (__bf16)v[1];
    b16x2 p1; p1[0] = (__bf16)v[2]; p1[1] = (__bf16)v[3];
    int2 r;
    r.x = __builtin_bit_cast(int, p0);
    r.y = __builtin_bit_cast(int, p1);
    return r;
}

// R9 = R8 row loop, but weight fragments come from block-cooperative COALESCED
// staging through LDS instead of per-wave scattered global loads (which were
// 8.4M 16B segment-requests chip-wide, all at kernel start). W1 -> wave0's LDS
// region, W2 -> wave1's region (bf16, pitch ROWP, same layout as X staging);
// after the frag reads + barrier, all regions revert to per-wave XT/OL use.
__global__ __launch_bounds__(256) void kron2_kernel(
    const float* __restrict__ data, const float* __restrict__ W1,
    const float* __restrict__ W2, float* __restrict__ out)
{
    __shared__ __align__(16) char smem[4][WBYTES];
    const int lane = threadIdx.x & 63;
    const int wv   = threadIdx.x >> 6;
    const int c    = lane & 15;
    const int g    = lane >> 4;
    short (*XT)[ROWP]  = reinterpret_cast<short(*)[ROWP]>(&smem[wv][0]);
    float* OL          = reinterpret_cast<float*>(&smem[wv][0]);
    short (*WR1)[ROWP] = reinterpret_cast<short(*)[ROWP]>(&smem[0][0]);
    short (*WR2)[ROWP] = reinterpret_cast<short(*)[ROWP]>(&smem[1][0]);

    // ---- block-cooperative coalesced weight staging ----
    // waves 0,1 stage W1 halves; waves 2,3 stage W2 halves. 8 x 1KB loads each.
    {
        const float* Wsrc = (wv < 2) ? W1 : W2;
        short (*WD)[ROWP] = (wv < 2) ? WR1 : WR2;
        const int base = (wv & 1) * 8;
        f32x4 t[8];
        #pragma unroll
        for (int j = 0; j < 8; ++j)
            t[j] = *reinterpret_cast<const f32x4*>(Wsrc + (base + j) * 256 + lane * 4);
        #pragma unroll
        for (int j = 0; j < 8; ++j)
            *reinterpret_cast<int2*>(&WD[(base + j) * 4 + g][c * 4]) = pack4(t[j]);
    }
    __syncthreads();

    const int w = (int)((blockIdx.x * blockDim.x + threadIdx.x) >> 6);

    // ---- issue row-0 loads now: in flight across frag reads + barrier ----
    f32x4 v[16];
    {
        const float* X0 = data + (size_t)(w * 2) * 4096;
        #pragma unroll
        for (int j = 0; j < 16; ++j)
            v[j] = *reinterpret_cast<const f32x4*>(X0 + j * 256 + lane * 4);
    }

    // ---- weight fragments from LDS (id8 for W2, kappa for W1) ----
    s16x8 w2f[4][2], w1f[4][2];
    #pragma unroll
    for (int t = 0; t < 4; ++t)
      #pragma unroll
      for (int kh = 0; kh < 2; ++kh) {
        w2f[t][kh] = *reinterpret_cast<const s16x8*>(&WR2[t * 16 + c][kh * 32 + g * 8]);
        s16x4 lo = *reinterpret_cast<const s16x4*>(&WR1[t * 16 + c][kh * 32 + g * 4]);
        s16x4 hi = *reinterpret_cast<const s16x4*>(&WR1[t * 16 + c][kh * 32 + 16 + g * 4]);
        s16x8 r;
        r[0] = lo[0]; r[1] = lo[1]; r[2] = lo[2]; r[3] = lo[3];
        r[4] = hi[0]; r[5] = hi[1]; r[6] = hi[2]; r[7] = hi[3];
        w1f[t][kh] = r;
      }
    __syncthreads();   // regions 0/1 revert to XT/OL use after this

    #pragma unroll
    for (int rr = 0; rr < 2; ++rr) {
        const int n = w * 2 + rr;

        // ---- stage v -> XT (bf16, pitch ROWP) ----
        #pragma unroll
        for (int j = 0; j < 16; ++j)
            *reinterpret_cast<int2*>(&XT[j * 4 + g][c * 4]) = pack4(v[j]);

        // ---- X fragments from LDS (id8 map) ----
        s16x8 xa[4][2];
        #pragma unroll
        for (int mt = 0; mt < 4; ++mt)
          #pragma unroll
          for (int kh = 0; kh < 2; ++kh)
            xa[mt][kh] = *reinterpret_cast<const s16x8*>(&XT[mt * 16 + c][kh * 32 + g * 8]);

        // ---- prefetch second row; in flight across all compute below ----
        if (rr == 0) {
            const float* Xn = data + (size_t)(n + 1) * 4096;
            #pragma unroll
            for (int j = 0; j < 16; ++j)
                v[j] = *reinterpret_cast<const f32x4*>(Xn + j * 256 + lane * 4);
        }

        // ---- stage 1: T = X @ W2^T (id8), nt-outer; T^T A-frags via kappa ----
        s16x8 a2[4][2];
        #pragma unroll
        for (int nt = 0; nt < 4; ++nt) {
            f32x4 acc[4];
            #pragma unroll
            for (int mt = 0; mt < 4; ++mt) {
                f32x4 a = {0.f, 0.f, 0.f, 0.f};
                a = mfma_bf16(xa[mt][0], w2f[nt][0], a);
                a = mfma_bf16(xa[mt][1], w2f[nt][1], a);
                acc[mt] = a;
            }
            a2[nt][0] = pack8(acc[0], acc[1]);
            a2[nt][1] = pack8(acc[2], acc[3]);
        }

        // ---- stage 2 + coalesced store, 32-row halves through OL (union) ----
        #pragma unroll
        for (int h2 = 0; h2 < 2; ++h2) {
            #pragma unroll
            for (int q = 0; q < 2; ++q) {
                const int it = h2 * 2 + q;
                #pragma unroll
                for (int jt = 0; jt < 4; ++jt) {
                    f32x4 a = {0.f, 0.f, 0.f, 0.f};
                    a = mfma_bf16(a2[jt][0], w1f[it][0], a);
                    a = mfma_bf16(a2[jt][1], w1f[it][1], a);
                    const int prow = q * 16 + c;
                    const int pcol = (jt * 16 + g * 4) ^ (c * 4);
                    *reinterpret_cast<f32x4*>(&OL[prow * 64 + pcol]) = a;
                }
            }
            #pragma unroll
            for (int s = 0; s < 8; ++s) {
                const int prow = s * 4 + (lane >> 4);
                const int pcol = ((lane & 15) * 4) ^ ((prow & 15) * 4);
                f32x4 o = *reinterpret_cast<const f32x4*>(&OL[prow * 64 + pcol]);
                *reinterpret_cast<f32x4*>(
                    out + (size_t)n * 4096 + h2 * 2048 + s * 256 + lane * 4) = o;
            }
            // compiler-only fence for OL region reuse (HW LDS is in-order per wave)
            asm volatile("" ::: "memory");
            __builtin_amdgcn_sched_barrier(0);
        }
        asm volatile("" ::: "memory");
        __builtin_amdgcn_sched_barrier(0);
    }
}

extern "C" void kernel_launch(void* const* d_in, const int* in_sizes, int n_in,
                              void* d_out, int out_size, void* d_ws, size_t ws_size,
                              hipStream_t stream) {
    const float* data = (const float*)d_in[0];
    const float* W1   = (const float*)d_in[1];
    const float* W2   = (const float*)d_in[2];
    float* out        = (float*)d_out;
    dim3 grid(NROWS / 8), block(256);   // 1024 blocks x 4 waves x 2 rows
    hipLaunchKernelGGL(kron2_kernel, grid, block, 0, stream, data, W1, W2, out);
}

// Round 10
// 45.339 us; speedup vs baseline: 1.1844x; 1.0330x over previous
//
#include <hip/hip_runtime.h>
#include <hip/hip_bf16.h>

typedef float  f32x4 __attribute__((ext_vector_type(4)));
typedef short  s16x4 __attribute__((ext_vector_type(4)));
typedef short  s16x8 __attribute__((ext_vector_type(8)));
typedef __bf16 b16x8 __attribute__((ext_vector_type(8)));
typedef __bf16 b16x2 __attribute__((ext_vector_type(2)));

#define NROWS  8192
#define ROWP   72      // X staging pitch (shorts)
#define WBYTES 9216    // per-wave LDS region: union of X-stage / O-stage / weight-stage

__device__ __forceinline__ f32x4 mfma_bf16(s16x8 a, s16x8 b, f32x4 c) {
    return __builtin_amdgcn_mfma_f32_16x16x32_bf16(
        __builtin_bit_cast(b16x8, a), __builtin_bit_cast(b16x8, b), c, 0, 0, 0);
}

__device__ __forceinline__ short f2b(float f) {
    return __builtin_bit_cast(short, (__bf16)f);
}

__device__ __forceinline__ s16x8 pack8(f32x4 a, f32x4 b) {
    s16x8 r;
    r[0] = f2b(a[0]); r[1] = f2b(a[1]); r[2] = f2b(a[2]); r[3] = f2b(a[3]);
    r[4] = f2b(b[0]); r[5] = f2b(b[1]); r[6] = f2b(b[2]); r[7] = f2b(b[3]);
    return r;
}

__device__ __forceinline__ int2 pack4(f32x4 v) {
    b16x2 p0; p0[0] = (__bf16)v[0]; p0[1] = (__bf16)v[1];
    b16x2 p1; p1[0] = (__bf16)v[2]; p1[1] = (__bf16)v[3];
    int2 r;
    r.x = __builtin_bit_cast(int, p0);
    r.y = __builtin_bit_cast(int, p1);
    return r;
}

// R10 = R9 (46.8us: all paths 1KB lane-contiguous; block-cooperative weight
// staging; register-transpose between stages; OL store-coalescing) with ONE
// change: global output stores are NON-TEMPORAL. Stores are full-line (8 x
// 128B per instruction) so NT cannot cause partial-line over-write (R3's
// failure mode was 64B scattered NT stores); marking the 128MB write stream
// evict-first keeps the 128MB input resident in the 256MB L3 across replays,
// cutting steady-state FETCH (was exactly half the input = L3 capacity split).
__global__ __launch_bounds__(256) void kron2_kernel(
    const float* __restrict__ data, const float* __restrict__ W1,
    const float* __restrict__ W2, float* __restrict__ out)
{
    __shared__ __align__(16) char smem[4][WBYTES];
    const int lane = threadIdx.x & 63;
    const int wv   = threadIdx.x >> 6;
    const int c    = lane & 15;
    const int g    = lane >> 4;
    short (*XT)[ROWP]  = reinterpret_cast<short(*)[ROWP]>(&smem[wv][0]);
    float* OL          = reinterpret_cast<float*>(&smem[wv][0]);
    short (*WR1)[ROWP] = reinterpret_cast<short(*)[ROWP]>(&smem[0][0]);
    short (*WR2)[ROWP] = reinterpret_cast<short(*)[ROWP]>(&smem[1][0]);

    // ---- block-cooperative coalesced weight staging ----
    {
        const float* Wsrc = (wv < 2) ? W1 : W2;
        short (*WD)[ROWP] = (wv < 2) ? WR1 : WR2;
        const int base = (wv & 1) * 8;
        f32x4 t[8];
        #pragma unroll
        for (int j = 0; j < 8; ++j)
            t[j] = *reinterpret_cast<const f32x4*>(Wsrc + (base + j) * 256 + lane * 4);
        #pragma unroll
        for (int j = 0; j < 8; ++j)
            *reinterpret_cast<int2*>(&WD[(base + j) * 4 + g][c * 4]) = pack4(t[j]);
    }
    __syncthreads();

    const int w = (int)((blockIdx.x * blockDim.x + threadIdx.x) >> 6);

    // ---- issue row-0 loads now: in flight across frag reads + barrier ----
    f32x4 v[16];
    {
        const float* X0 = data + (size_t)(w * 2) * 4096;
        #pragma unroll
        for (int j = 0; j < 16; ++j)
            v[j] = *reinterpret_cast<const f32x4*>(X0 + j * 256 + lane * 4);
    }

    // ---- weight fragments from LDS (id8 for W2, kappa for W1) ----
    s16x8 w2f[4][2], w1f[4][2];
    #pragma unroll
    for (int t = 0; t < 4; ++t)
      #pragma unroll
      for (int kh = 0; kh < 2; ++kh) {
        w2f[t][kh] = *reinterpret_cast<const s16x8*>(&WR2[t * 16 + c][kh * 32 + g * 8]);
        s16x4 lo = *reinterpret_cast<const s16x4*>(&WR1[t * 16 + c][kh * 32 + g * 4]);
        s16x4 hi = *reinterpret_cast<const s16x4*>(&WR1[t * 16 + c][kh * 32 + 16 + g * 4]);
        s16x8 r;
        r[0] = lo[0]; r[1] = lo[1]; r[2] = lo[2]; r[3] = lo[3];
        r[4] = hi[0]; r[5] = hi[1]; r[6] = hi[2]; r[7] = hi[3];
        w1f[t][kh] = r;
      }
    __syncthreads();   // regions 0/1 revert to XT/OL use after this

    #pragma unroll
    for (int rr = 0; rr < 2; ++rr) {
        const int n = w * 2 + rr;

        // ---- stage v -> XT (bf16, pitch ROWP) ----
        #pragma unroll
        for (int j = 0; j < 16; ++j)
            *reinterpret_cast<int2*>(&XT[j * 4 + g][c * 4]) = pack4(v[j]);

        // ---- X fragments from LDS (id8 map) ----
        s16x8 xa[4][2];
        #pragma unroll
        for (int mt = 0; mt < 4; ++mt)
          #pragma unroll
          for (int kh = 0; kh < 2; ++kh)
            xa[mt][kh] = *reinterpret_cast<const s16x8*>(&XT[mt * 16 + c][kh * 32 + g * 8]);

        // ---- prefetch second row; in flight across all compute below ----
        if (rr == 0) {
            const float* Xn = data + (size_t)(n + 1) * 4096;
            #pragma unroll
            for (int j = 0; j < 16; ++j)
                v[j] = *reinterpret_cast<const f32x4*>(Xn + j * 256 + lane * 4);
        }

        // ---- stage 1: T = X @ W2^T (id8), nt-outer; T^T A-frags via kappa ----
        s16x8 a2[4][2];
        #pragma unroll
        for (int nt = 0; nt < 4; ++nt) {
            f32x4 acc[4];
            #pragma unroll
            for (int mt = 0; mt < 4; ++mt) {
                f32x4 a = {0.f, 0.f, 0.f, 0.f};
                a = mfma_bf16(xa[mt][0], w2f[nt][0], a);
                a = mfma_bf16(xa[mt][1], w2f[nt][1], a);
                acc[mt] = a;
            }
            a2[nt][0] = pack8(acc[0], acc[1]);
            a2[nt][1] = pack8(acc[2], acc[3]);
        }

        // ---- stage 2 + coalesced store, 32-row halves through OL (union) ----
        #pragma unroll
        for (int h2 = 0; h2 < 2; ++h2) {
            #pragma unroll
            for (int q = 0; q < 2; ++q) {
                const int it = h2 * 2 + q;
                #pragma unroll
                for (int jt = 0; jt < 4; ++jt) {
                    f32x4 a = {0.f, 0.f, 0.f, 0.f};
                    a = mfma_bf16(a2[jt][0], w1f[it][0], a);
                    a = mfma_bf16(a2[jt][1], w1f[it][1], a);
                    const int prow = q * 16 + c;
                    const int pcol = (jt * 16 + g * 4) ^ (c * 4);
                    *reinterpret_cast<f32x4*>(&OL[prow * 64 + pcol]) = a;
                }
            }
            #pragma unroll
            for (int s = 0; s < 8; ++s) {
                const int prow = s * 4 + (lane >> 4);
                const int pcol = ((lane & 15) * 4) ^ ((prow & 15) * 4);
                f32x4 o = *reinterpret_cast<const f32x4*>(&OL[prow * 64 + pcol]);
                __builtin_nontemporal_store(o, reinterpret_cast<f32x4*>(
                    out + (size_t)n * 4096 + h2 * 2048 + s * 256 + lane * 4));
            }
            // compiler-only fence for OL region reuse (HW LDS is in-order per wave)
            asm volatile("" ::: "memory");
            __builtin_amdgcn_sched_barrier(0);
        }
        asm volatile("" ::: "memory");
        __builtin_amdgcn_sched_barrier(0);
    }
}

extern "C" void kernel_launch(void* const* d_in, const int* in_sizes, int n_in,
                              void* d_out, int out_size, void* d_ws, size_t ws_size,
                              hipStream_t stream) {
    const float* data = (const float*)d_in[0];
    const float* W1   = (const float*)d_in[1];
    const float* W2   = (const float*)d_in[2];
    float* out        = (float*)d_out;
    dim3 grid(NROWS / 8), block(256);   // 1024 blocks x 4 waves x 2 rows
    hipLaunchKernelGGL(kron2_kernel, grid, block, 0, stream, data, W1, W2, out);
}